// Round 10
// baseline (124.696 us; speedup 1.0000x reference)
//
#include <hip/hip_runtime.h>
#include <hip/hip_bf16.h>

// GConv: out = relu( Agg(support) + x@loop_W + bias )
// R9: R8 + agg restructured as XCD-pinned feature-quarters in ONE dispatch:
//     block b -> XCD (b&7) [HW round-robin], quarter q=(b&7)>>1, so each XCD's
//     L2 only sees a 2.56MB sup slice (was 10.2MB x 8 XCDs = 116MB refetch).

#define NN 10000
#define DK 256
#define DO 256
#define MT 20000      // B*N rows
#define SCAN_T 1024
#define SCAN_C 10     // 10240 >= NN
#define CVB 2500      // cvt blocks: 640000 short8 / 256

typedef short short8 __attribute__((ext_vector_type(8)));
typedef float f32x4 __attribute__((ext_vector_type(4)));

#define GLOAD_LDS(G, L) __builtin_amdgcn_global_load_lds(                 \
    (const __attribute__((address_space(1))) void*)(G),                   \
    (__attribute__((address_space(3))) void*)(L), 16, 0, 0)

__device__ inline unsigned short f2bf(float f) {
    unsigned int u = __float_as_uint(f);
    u = (u + 0x7FFFu + ((u >> 16) & 1u)) >> 16;   // round-nearest-even
    return (unsigned short)u;
}
__device__ inline float bf2f(unsigned short s) {
    return __uint_as_float(((unsigned int)s) << 16);
}

// ---------------- prep: [0,CVB) cvt X->bf16 | [CVB,CVB+32) transpose W/LW | rest hist ----------------
__global__ __launch_bounds__(256) void prep_kernel(
    const float* __restrict__ X, unsigned short* __restrict__ Xb,
    const float* __restrict__ W, const float* __restrict__ LW,
    unsigned short* __restrict__ Wt, unsigned short* __restrict__ LWt,
    const int* __restrict__ rows, int* __restrict__ counts, int E)
{
    __shared__ float tile[64][65];
    const int bid = blockIdx.x;
    if (bid < CVB) {
        const int i = bid * 256 + threadIdx.x;   // < 640000 always
        const float4 a = ((const float4*)X)[2 * i];
        const float4 b = ((const float4*)X)[2 * i + 1];
        short8 o;
        o[0] = (short)f2bf(a.x); o[1] = (short)f2bf(a.y);
        o[2] = (short)f2bf(a.z); o[3] = (short)f2bf(a.w);
        o[4] = (short)f2bf(b.x); o[5] = (short)f2bf(b.y);
        o[6] = (short)f2bf(b.z); o[7] = (short)f2bf(b.w);
        *(short8*)&Xb[(size_t)i * 8] = o;
    } else if (bid < CVB + 32) {
        const int zb = bid - CVB;
        const int z = zb >> 4, rem = zb & 15;
        const int k0 = (rem >> 2) * 64, c0 = (rem & 3) * 64;
        const float* src = z ? LW : W;
        unsigned short* dst = z ? LWt : Wt;
        #pragma unroll
        for (int it = 0; it < 16; ++it) {
            const int u = it * 256 + threadIdx.x;
            const int i = u >> 6, j = u & 63;
            tile[i][j] = src[(size_t)(k0 + i) * DO + c0 + j];
        }
        __syncthreads();
        #pragma unroll
        for (int it = 0; it < 16; ++it) {
            const int u = it * 256 + threadIdx.x;
            const int j = u >> 6, i = u & 63;
            dst[(size_t)(c0 + j) * DK + k0 + i] = f2bf(tile[i][j]);
        }
    } else {
        const int e = (bid - CVB - 32) * 256 + threadIdx.x;
        if (e < E) atomicAdd(&counts[rows[e]], 1);
    }
}

// ---------------- scan: exclusive prefix over counts -> offsets, cursor ----------------
__global__ __launch_bounds__(SCAN_T) void scan_rows(
    const int* __restrict__ counts, int* __restrict__ offsets,
    int* __restrict__ cursor)
{
    __shared__ int sums[SCAN_T];
    const int t = threadIdx.x;
    int local[SCAN_C];
    int s = 0;
    const int base = t * SCAN_C;
    #pragma unroll
    for (int i = 0; i < SCAN_C; ++i) {
        const int idx = base + i;
        const int c = (idx < NN) ? counts[idx] : 0;
        local[i] = s;
        s += c;
    }
    sums[t] = s;
    __syncthreads();
    for (int off = 1; off < SCAN_T; off <<= 1) {
        int u = (t >= off) ? sums[t - off] : 0;
        __syncthreads();
        sums[t] += u;
        __syncthreads();
    }
    const int excl = (t == 0) ? 0 : sums[t - 1];
    #pragma unroll
    for (int i = 0; i < SCAN_C; ++i) {
        const int idx = base + i;
        if (idx < NN) {
            const int o = excl + local[i];
            offsets[idx] = o;
            cursor[idx]  = o;
        }
    }
}

// ---------------- main: blocks [0,gemmBlocks) dual GEMM via global_load_lds; rest: scatter ----------------
__global__ __launch_bounds__(256) void main_kernel(
    const unsigned short* __restrict__ Xb, const unsigned short* __restrict__ Wt,
    const unsigned short* __restrict__ LWt, const float* __restrict__ bias,
    unsigned short* __restrict__ sup, float* __restrict__ outv,
    const int* __restrict__ rows, const int* __restrict__ cols,
    const float* __restrict__ vals, int* __restrict__ cursor,
    float2* __restrict__ epack, int E, int gemmBlocks)
{
    __shared__ unsigned short Abuf[8 * 64 * 8];
    __shared__ unsigned short BbufW[8 * 64 * 8];
    __shared__ unsigned short BbufL[8 * 64 * 8];

    if ((int)blockIdx.x >= gemmBlocks) {
        const int e = (blockIdx.x - gemmBlocks) * 256 + threadIdx.x;
        if (e < E) {
            const int p = atomicAdd(&cursor[rows[e]], 1);
            epack[p] = make_float2(__int_as_float(cols[e]), vals[e]);
        }
        return;
    }

    const int t = threadIdx.x;
    const int wid = t >> 6, lane = t & 63;
    const int wm = wid >> 1, wn = wid & 1;
    const int m0 = (blockIdx.x >> 2) * 64;
    const int n0 = (blockIdx.x & 3) * 64;

    f32x4 accW[2][2], accL[2][2];
    #pragma unroll
    for (int i = 0; i < 2; ++i)
        #pragma unroll
        for (int j = 0; j < 2; ++j) {
            accW[i][j] = (f32x4){0.f, 0.f, 0.f, 0.f};
            accL[i][j] = (f32x4){0.f, 0.f, 0.f, 0.f};
        }

    for (int k0 = 0; k0 < DK; k0 += 64) {
        #pragma unroll
        for (int c = 0; c < 2; ++c) {
            const int kg = c * 4 + wid;                 // wave-uniform
            const int src_r = lane ^ kg;                // pre-swizzled source
            const size_t aoff = (size_t)(m0 + src_r) * DK + k0 + kg * 8;
            const size_t boff = (size_t)(n0 + src_r) * DK + k0 + kg * 8;
            GLOAD_LDS(&Xb[aoff],  &Abuf[(c * 256 + wid * 64) * 8]);
            GLOAD_LDS(&Wt[boff],  &BbufW[(c * 256 + wid * 64) * 8]);
            GLOAD_LDS(&LWt[boff], &BbufL[(c * 256 + wid * 64) * 8]);
        }
        __syncthreads();
        #pragma unroll
        for (int s = 0; s < 2; ++s) {             // two k=32 substeps
            const int kg = s * 4 + (lane >> 4);
            short8 af[2], bW[2], bL[2];
            #pragma unroll
            for (int i = 0; i < 2; ++i) {
                const int row = wm * 32 + i * 16 + (lane & 15);
                af[i] = *(const short8*)&Abuf[((size_t)kg * 64 + (row ^ kg)) * 8];
            }
            #pragma unroll
            for (int j = 0; j < 2; ++j) {
                const int col = wn * 32 + j * 16 + (lane & 15);
                bW[j] = *(const short8*)&BbufW[((size_t)kg * 64 + (col ^ kg)) * 8];
                bL[j] = *(const short8*)&BbufL[((size_t)kg * 64 + (col ^ kg)) * 8];
            }
            #pragma unroll
            for (int i = 0; i < 2; ++i)
                #pragma unroll
                for (int j = 0; j < 2; ++j) {
                    accW[i][j] = __builtin_amdgcn_mfma_f32_16x16x32_bf16(
                        af[i], bW[j], accW[i][j], 0, 0, 0);
                    accL[i][j] = __builtin_amdgcn_mfma_f32_16x16x32_bf16(
                        af[i], bL[j], accL[i][j], 0, 0, 0);
                }
        }
        __syncthreads();
    }

    const int rbase = m0 + wm * 32;
    const int cbase = n0 + wn * 32;
    #pragma unroll
    for (int i = 0; i < 2; ++i)
        #pragma unroll
        for (int q = 0; q < 4; ++q) {
            const int row = rbase + i * 16 + (lane >> 4) * 4 + q;
            if (row < MT) {
                #pragma unroll
                for (int j = 0; j < 2; ++j) {
                    const int col = cbase + j * 16 + (lane & 15);
                    sup[(size_t)row * DO + col] = f2bf(accW[i][j][q]);
                    outv[(size_t)row * DO + col] = accL[i][j][q] + bias[col];
                }
            }
        }
}

// ---------------- aggregate + ReLU: XCD-pinned feature quarters ----------------
// block b -> XCD (b&7) by HW round-robin; quarter q=(b&7)>>1 -> each XCD
// gathers only sup[:, :, q*64 .. q*64+64) = 2.56MB, fits 4MB private L2.
// wave = (row, quarter); lanes: batch = lane>>5, feats = (lane&31)*2 (ushort2).
__global__ __launch_bounds__(256) void agg_relu(
    const unsigned short* __restrict__ sup, const float2* __restrict__ epack,
    const int* __restrict__ offsets, const int* __restrict__ counts,
    float* __restrict__ outv)
{
    const int bid = blockIdx.x;
    const int xcd = bid & 7;
    const int q = xcd >> 1;
    const int sub = (bid >> 3) * 2 + (xcd & 1);   // [0, 2500)
    const int wid = threadIdx.x >> 6, lane = threadIdx.x & 63;
    const int r = sub * 4 + wid;                  // [0, 10000)
    const int bb = lane >> 5;                     // batch
    const int f = q * 64 + (lane & 31) * 2;
    const int start = offsets[r];
    const int deg   = counts[r];
    const size_t supb = (size_t)bb * NN * DO + f;

    float a0 = 0.f, a1 = 0.f;
    #pragma unroll 8
    for (int i = 0; i < deg; ++i) {
        const float2 ep = epack[start + i];
        const int col = __float_as_int(ep.x);
        const float v = ep.y;
        const ushort2 s = *(const ushort2*)&sup[supb + (size_t)col * DO];
        a0 += v * bf2f(s.x);
        a1 += v * bf2f(s.y);
    }

    float* o = &outv[((size_t)bb * NN + r) * DO + f];
    float2 t2 = *(const float2*)o;
    t2.x = fmaxf(t2.x + a0, 0.f);
    t2.y = fmaxf(t2.y + a1, 0.f);
    *(float2*)o = t2;
}

extern "C" void kernel_launch(void* const* d_in, const int* in_sizes, int n_in,
                              void* d_out, int out_size, void* d_ws, size_t ws_size,
                              hipStream_t stream)
{
    const float* x    = (const float*)d_in[0];
    const float* W    = (const float*)d_in[1];
    const float* LW   = (const float*)d_in[2];
    const float* bias = (const float*)d_in[3];
    const float* ev   = (const float*)d_in[4];
    const int*   rows = (const int*)d_in[5];
    const int*   cols = (const int*)d_in[6];
    float* out = (float*)d_out;

    const int E = in_sizes[4];
    const int EB = (E + 255) / 256;
    const int gemmBlocks = ((MT + 63) / 64) * 4;    // 313*4 = 1252

    // workspace layout (Xb padded to 20032 rows: OOB tile-312 reads hit
    // deterministic ws bytes; those acc rows are discarded by the epilogue guard)
    char* wsb = (char*)d_ws;
    unsigned short* Wt    = (unsigned short*)wsb;               // 131,072 B
    unsigned short* LWt   = (unsigned short*)(wsb + 131072);    // 131,072 B
    unsigned short* Xb    = (unsigned short*)(wsb + 262144);    // 20032*256*2 = 10,256,384 B
    unsigned short* supb  = (unsigned short*)(wsb + 10518528);  // 10,240,000 B
    int* counts  = (int*)(wsb + 20758528);                      // 40,000 B
    int* offsets = (int*)(wsb + 20798528);                      // 40,000 B
    int* cursor  = (int*)(wsb + 20838528);                      // 40,000 B
    float2* epack = (float2*)(wsb + 20878528);                  // 8*E B

    hipMemsetAsync(counts, 0, NN * sizeof(int), stream);

    prep_kernel<<<CVB + 32 + EB, 256, 0, stream>>>(
        x, Xb, W, LW, Wt, LWt, rows, counts, E);
    scan_rows<<<1, SCAN_T, 0, stream>>>(counts, offsets, cursor);
    main_kernel<<<gemmBlocks + EB, 256, 0, stream>>>(
        Xb, Wt, LWt, bias, supb, out, rows, cols, ev, cursor, epack, E, gemmBlocks);

    // 10000 blocks: 4 waves/block, one (row, quarter) per wave, XCD-pinned.
    agg_relu<<<NN, 256, 0, stream>>>(supb, epack, offsets, counts, out);
}